// Round 1
// 152.719 us; speedup vs baseline: 1.0424x; 1.0424x over previous
//
#include <hip/hip_runtime.h>
#include <hip/hip_bf16.h>
#include <math.h>

#define LTOK 512
#define DDIM 512
#define NEXP 32
#define HDIM 512

typedef __attribute__((ext_vector_type(8))) short short8;
typedef __attribute__((ext_vector_type(4))) float floatx4;

// round-to-nearest-even fp32->bf16, packed pair: low16 = rne(a), high16 = rne(b)
__device__ __forceinline__ unsigned bpack(float a, float b) {
    unsigned ua = __float_as_uint(a), ub = __float_as_uint(b);
    ua += 0x7FFFu + ((ua >> 16) & 1u);
    ub += 0x7FFFu + ((ub >> 16) & 1u);
    return (ua >> 16) | (ub & 0xFFFF0000u);
}

// Async global->LDS DMA (zero VGPR cost). LDS dst = wave-uniform base + lane*size.
__device__ __forceinline__ void stage16(const float* g, void* l) {
    __builtin_amdgcn_global_load_lds(
        (const __attribute__((address_space(1))) void*)g,
        (__attribute__((address_space(3))) void*)l, 16, 0, 0);
}
__device__ __forceinline__ void stage4(const float* g, void* l) {
    __builtin_amdgcn_global_load_lds(
        (const __attribute__((address_space(1))) void*)g,
        (__attribute__((address_space(3))) void*)l, 4, 0, 0);
}

// Raw barrier WITHOUT the compiler's s_waitcnt vmcnt(0) drain (so async DMA
// stays in flight across it). Own-wave LDS ops drained for scan correctness.
#define RAW_BARRIER() do { \
    asm volatile("s_waitcnt lgkmcnt(0)" ::: "memory"); \
    __builtin_amdgcn_s_barrier(); \
} while (0)

// ws layout (bytes):
//   [0, 4K)        easgn: int[1024]   easgn[2t+k] = expert of token t's k-th pick
//   [4K, 8K)       wts:   float[1024] = routing weight * per_expert_scale
//   [8K, +512K)    xb:    512x512 bf16 (x rounded to bf16)
//   [532480, +1M)  act:   1024x512 bf16 (slot-indexed activated gate output)

// 256 threads/token-block: 4 waves split the logits K-dim (64 Wr loads/lane
// instead of 256 -> 4x shorter L2 latency chain, the router's critical path).
__global__ __launch_bounds__(256) void router_kernel(
    const float* __restrict__ x, const float* __restrict__ rs,
    const float* __restrict__ Wr, const float* __restrict__ pes,
    int* __restrict__ easgn, float* __restrict__ wts,
    short* __restrict__ xb, float* __restrict__ out)
{
    const int t = blockIdx.x;
    const int tid = threadIdx.x;
    const int lane = tid & 63;
    const int wv = tid >> 6;

    float xv[2];
    float ss = 0.f;
#pragma unroll
    for (int j = 0; j < 2; ++j) {
        xv[j] = x[t * DDIM + j * 256 + tid];
        ss += xv[j] * xv[j];
    }
    // emit bf16 copy of x for the expert GEMMs; zero this token's out row
#pragma unroll
    for (int j = 0; j < 2; ++j) {
        xb[t * DDIM + j * 256 + tid] = (short)(bpack(xv[j], 0.f) & 0xFFFFu);
        out[t * DDIM + j * 256 + tid] = 0.f;
    }

#pragma unroll
    for (int o = 32; o > 0; o >>= 1) ss += __shfl_xor(ss, o);
    __shared__ float sred[4];
    if (lane == 0) sred[wv] = ss;
    __syncthreads();
    ss = (sred[0] + sred[1]) + (sred[2] + sred[3]);
    const float var = ss * (1.0f / 512.0f);
    const float coef = rsqrtf(var + 1e-6f) * rsqrtf(512.0f);

    __shared__ float ri[DDIM];
#pragma unroll
    for (int j = 0; j < 2; ++j) {
        const int d = j * 256 + tid;
        ri[d] = xv[j] * coef * rs[d];
    }
    __syncthreads();

    // logits: tid&31 -> expert, tid>>5 -> 1/8th of D (64 d each)
    const int e = tid & 31;
    const int seg = tid >> 5;
    const int dbeg = seg * 64;
    float l0 = 0.f, l1 = 0.f, l2 = 0.f, l3 = 0.f;
#pragma unroll 4
    for (int d = dbeg; d < dbeg + 64; d += 4) {
        l0 = fmaf(ri[d + 0], Wr[(d + 0) * NEXP + e], l0);
        l1 = fmaf(ri[d + 1], Wr[(d + 1) * NEXP + e], l1);
        l2 = fmaf(ri[d + 2], Wr[(d + 2) * NEXP + e], l2);
        l3 = fmaf(ri[d + 3], Wr[(d + 3) * NEXP + e], l3);
    }
    __shared__ float lpart[8][NEXP];
    lpart[seg][e] = (l0 + l1) + (l2 + l3);
    __syncthreads();

    __shared__ float lgs[NEXP];
    if (tid < NEXP) {
        float v = 0.f;
#pragma unroll
        for (int s = 0; s < 8; ++s) v += lpart[s][tid];
        lgs[tid] = v;
    }
    __syncthreads();

    if (tid == 0) {
        int i0 = 0; float m0 = lgs[0];
        for (int i = 1; i < NEXP; ++i) if (lgs[i] > m0) { m0 = lgs[i]; i0 = i; }
        int i1 = -1; float m1 = -1e30f;
        for (int i = 0; i < NEXP; ++i) if (i != i0 && lgs[i] > m1) { m1 = lgs[i]; i1 = i; }
        // softmax denom cancels against renorm: weights depend only on top-2 logits
        const float e1 = expf(m1 - m0);
        const float inv = 1.0f / (1.0f + e1);
        easgn[2 * t]     = i0;
        easgn[2 * t + 1] = i1;
        wts[2 * t]     = inv * pes[i0];
        wts[2 * t + 1] = e1 * inv * pes[i1];
    }
}

// grid (32, 32): blockIdx.x = 16-wide h tile, blockIdx.y = expert.
// 4 waves: wv = (khalf<<1)|gate. Wave's B chunk (16 h x 256 k fp32 = 16 KB) is
// staged to LDS via async global_load_lds in FRAGMENT ORDER. Changes this round:
//  - toks/lcnt de-aliased from the stage buffer so the self-select scan runs
//    UNDER the DMA flight (raw barriers: no vmcnt(0) drain).
//  - split pack wait: vmcnt(8) covers ks0..3 (first 8 KB/wave), pack them while
//    the last 8 KB is still in flight, then vmcnt(0) for ks4..7.
// red (8 KB) still aliases the stage (dead after pack; barrier in between).
// ~67.6 KB LDS -> 2 blocks/CU.
__global__ __launch_bounds__(256, 2) void gates_kernel(
    const short* __restrict__ xb, const float* __restrict__ G,
    const int* __restrict__ easgn, short* __restrict__ act)
{
    const int e  = blockIdx.y;
    const int h0 = blockIdx.x * 16;
    const int tid = threadIdx.x;
    const int wv   = tid >> 6;
    const int g    = wv & 1;    // gate index
    const int kh   = wv >> 1;   // K half
    const int lane = tid & 63;
    const int n    = lane & 15;
    const int quad = lane >> 4;

    __shared__ __align__(16) char smem[65536];
    float (*red)[2][4][64] = (float(*)[2][4][64])smem;   // [4][2][4][64] = 8 KB, aliases stage
    __shared__ int toks[LTOK];                           // de-aliased (scan overlaps DMA)
    __shared__ int lcnt;

    // easgn load issued FIRST (oldest vmcnt slot -> scan waits only on it)
    const int4 eg = ((const int4*)easgn)[tid];   // slots 4*tid .. 4*tid+3

    // ---- async stage: 16 instrs x 1 KB per wave ----
    const float* Gl = G + ((size_t)((e * 2 + g) * HDIM) + h0 + n) * DDIM + kh * 256 + quad * 8;
    char* const swv = smem + wv * 16384;
#pragma unroll
    for (int ks = 0; ks < 8; ++ks) {
#pragma unroll
        for (int half = 0; half < 2; ++half)
            stage16(Gl + ks * 32 + half * 4, swv + (ks * 2 + half) * 1024);
    }

    // ---- self-select scan, overlapped with the DMA flight ----
    if (tid == 0) lcnt = 0;
    RAW_BARRIER();
    if (eg.x == e) { int p = atomicAdd(&lcnt, 1); toks[p] = 4 * tid; }
    if (eg.y == e) { int p = atomicAdd(&lcnt, 1); toks[p] = 4 * tid + 1; }
    if (eg.z == e) { int p = atomicAdd(&lcnt, 1); toks[p] = 4 * tid + 2; }
    if (eg.w == e) { int p = atomicAdd(&lcnt, 1); toks[p] = 4 * tid + 3; }
    RAW_BARRIER();
    const int Ne = lcnt;
    if (Ne == 0) { __builtin_amdgcn_s_waitcnt(0x0f70); return; }   // drain DMA before exit

    // ---- pack to register fragments, split-wait ----
    short8 Bg[8];
    __builtin_amdgcn_s_waitcnt(0x0f78);   // vmcnt(8): eg + ks0..3 landed
    __builtin_amdgcn_sched_barrier(0);
#pragma unroll
    for (int ks = 0; ks < 4; ++ks) {
        const floatx4 u0 = *(const floatx4*)(swv + ks * 2048 + lane * 16);
        const floatx4 u1 = *(const floatx4*)(swv + ks * 2048 + 1024 + lane * 16);
        union { short8 s; unsigned u[4]; } B;
        B.u[0] = bpack(u0.x, u0.y);
        B.u[1] = bpack(u0.z, u0.w);
        B.u[2] = bpack(u1.x, u1.y);
        B.u[3] = bpack(u1.z, u1.w);
        Bg[ks] = B.s;
    }
    __builtin_amdgcn_s_waitcnt(0x0f70);   // vmcnt(0): ks4..7 landed
    __builtin_amdgcn_sched_barrier(0);
#pragma unroll
    for (int ks = 4; ks < 8; ++ks) {
        const floatx4 u0 = *(const floatx4*)(swv + ks * 2048 + lane * 16);
        const floatx4 u1 = *(const floatx4*)(swv + ks * 2048 + 1024 + lane * 16);
        union { short8 s; unsigned u[4]; } B;
        B.u[0] = bpack(u0.x, u0.y);
        B.u[1] = bpack(u0.z, u0.w);
        B.u[2] = bpack(u1.x, u1.y);
        B.u[3] = bpack(u1.z, u1.w);
        Bg[ks] = B.s;
    }
    __syncthreads();   // all packs done before red overlays the stage

    const short* xbh = xb + kh * 256;

    for (int mb = 0; mb < Ne; mb += 32) {
        int arow[2];
#pragma unroll
        for (int i = 0; i < 2; ++i) {
            int s = mb + i * 16 + n;
            arow[i] = toks[s < Ne ? s : Ne - 1] >> 1;   // token index
        }
        floatx4 acc[2] = {};
#pragma unroll
        for (int ks = 0; ks < 8; ++ks) {
            const int ko = ks * 32 + quad * 8;
#pragma unroll
            for (int i = 0; i < 2; ++i) {
                const short8 A = *(const short8*)(xbh + (size_t)arow[i] * DDIM + ko);
                acc[i] = __builtin_amdgcn_mfma_f32_16x16x32_bf16(A, Bg[ks], acc[i], 0, 0, 0);
            }
        }
#pragma unroll
        for (int i = 0; i < 2; ++i)
#pragma unroll
            for (int r = 0; r < 4; ++r)
                red[wv][i][r][lane] = acc[i][r];
        __syncthreads();

        // epilogue: wave handles m-tile (wv&1), regs {2u,2u+1}, u=wv>>1.
        // C/D: col = lane&15, row = quad*4 + r.
        {
            const int i = wv & 1;
            const int u = wv >> 1;
#pragma unroll
            for (int rr = 0; rr < 2; ++rr) {
                const int r = u * 2 + rr;
                const int s = mb + i * 16 + quad * 4 + r;
                if (s < Ne) {
                    const int a = toks[s];   // slot id = act row
                    const float g0 = red[0][i][r][lane] + red[2][i][r][lane];
                    const float g1 = red[1][i][r][lane] + red[3][i][r][lane];
                    // gelu_tanh(g0) = g0 * sigmoid(2*u)
                    const float uu = 0.7978845608f * (g0 + 0.044715f * g0 * g0 * g0);
                    const float sg = 1.0f / (1.0f + __expf(-2.0f * uu));
                    const float v = g0 * sg * g1;
                    act[(size_t)a * HDIM + h0 + n] = (short)(bpack(v, 0.f) & 0xFFFFu);
                }
            }
        }
        __syncthreads();
    }
}

// grid (32, 32): blockIdx.x = 16-wide d tile, blockIdx.y = expert.
// 4 waves = K quarters (128 h). Same changes: scan under DMA flight (raw
// barriers), split pack wait (vmcnt(16) covers ks0,1 = first 4 KB/wave).
// wts preloaded as float4 alongside easgn so the scan issues no new VMEM
// (keeps the split-wait vmcnt accounting exact). ~45 KB LDS.
__global__ __launch_bounds__(256, 2) void linear_kernel(
    const short* __restrict__ act, const float* __restrict__ Wl,
    const int* __restrict__ easgn, const float* __restrict__ wts,
    float* __restrict__ out)
{
    const int e  = blockIdx.y;
    const int d0 = blockIdx.x * 16;
    const int tid = threadIdx.x;
    const int wv   = tid >> 6;
    const int lane = tid & 63;
    const int n    = lane & 15;
    const int quad = lane >> 4;

    __shared__ __align__(16) float stage[4][2048];   // 8 KB per wave
    __shared__ float red[4][2][4][64];               // 8 KB
    __shared__ int   toks[LTOK];
    __shared__ float wsl[LTOK];
    __shared__ int   lcnt;

    // issued first: oldest vmcnt slots
    const int4 eg = ((const int4*)easgn)[tid];
    const float4 wt4 = ((const float4*)wts)[tid];

    // ---- async stage: 32 instrs x 256 B per wave ----
    const float* Wbase = Wl + ((size_t)e * HDIM + wv * 128 + quad * 8) * DDIM + d0 + n;
#pragma unroll
    for (int ks = 0; ks < 4; ++ks) {
#pragma unroll
        for (int j = 0; j < 8; ++j)
            stage4(Wbase + (size_t)(ks * 32 + j) * DDIM, (char*)&stage[wv][0] + (ks * 8 + j) * 256);
    }

    // ---- self-select scan, overlapped with the DMA flight ----
    if (tid == 0) lcnt = 0;
    RAW_BARRIER();
    if (eg.x == e) { int p = atomicAdd(&lcnt, 1); toks[p] = 4 * tid;     wsl[p] = wt4.x; }
    if (eg.y == e) { int p = atomicAdd(&lcnt, 1); toks[p] = 4 * tid + 1; wsl[p] = wt4.y; }
    if (eg.z == e) { int p = atomicAdd(&lcnt, 1); toks[p] = 4 * tid + 2; wsl[p] = wt4.z; }
    if (eg.w == e) { int p = atomicAdd(&lcnt, 1); toks[p] = 4 * tid + 3; wsl[p] = wt4.w; }
    RAW_BARRIER();
    const int Ne = lcnt;
    if (Ne == 0) { __builtin_amdgcn_s_waitcnt(0x0f70); return; }   // drain DMA before exit

    // ---- pack, split-wait ----
    short8 Bl[4];
    __builtin_amdgcn_s_waitcnt(0x4f70);   // vmcnt(16): eg+wt4+ks0,1 landed
    __builtin_amdgcn_sched_barrier(0);
#pragma unroll
    for (int ks = 0; ks < 2; ++ks) {
        float w[8];
#pragma unroll
        for (int j = 0; j < 8; ++j)
            w[j] = stage[wv][(ks * 8 + j) * 64 + lane];
        union { short8 s; unsigned u[4]; } B;
        B.u[0] = bpack(w[0], w[1]);
        B.u[1] = bpack(w[2], w[3]);
        B.u[2] = bpack(w[4], w[5]);
        B.u[3] = bpack(w[6], w[7]);
        Bl[ks] = B.s;
    }
    __builtin_amdgcn_s_waitcnt(0x0f70);   // vmcnt(0): ks2,3 landed
    __builtin_amdgcn_sched_barrier(0);
#pragma unroll
    for (int ks = 2; ks < 4; ++ks) {
        float w[8];
#pragma unroll
        for (int j = 0; j < 8; ++j)
            w[j] = stage[wv][(ks * 8 + j) * 64 + lane];
        union { short8 s; unsigned u[4]; } B;
        B.u[0] = bpack(w[0], w[1]);
        B.u[1] = bpack(w[2], w[3]);
        B.u[2] = bpack(w[4], w[5]);
        B.u[3] = bpack(w[6], w[7]);
        Bl[ks] = B.s;
    }

    for (int mb = 0; mb < Ne; mb += 32) {
        int arow[2];
#pragma unroll
        for (int i = 0; i < 2; ++i) {
            int s = mb + i * 16 + n;
            arow[i] = toks[s < Ne ? s : Ne - 1];   // slot id = act row
        }
        floatx4 acc[2] = {};
#pragma unroll
        for (int ks = 0; ks < 4; ++ks) {
            const int ko = wv * 128 + ks * 32 + quad * 8;
#pragma unroll
            for (int i = 0; i < 2; ++i) {
                const short8 A = *(const short8*)(act + (size_t)arow[i] * HDIM + ko);
                acc[i] = __builtin_amdgcn_mfma_f32_16x16x32_bf16(A, Bl[ks], acc[i], 0, 0, 0);
            }
        }
#pragma unroll
        for (int i = 0; i < 2; ++i)
#pragma unroll
            for (int r = 0; r < 4; ++r)
                red[wv][i][r][lane] = acc[i][r];
        __syncthreads();

        {
            const int i = wv & 1;
            const int u = wv >> 1;
#pragma unroll
            for (int rr = 0; rr < 2; ++rr) {
                const int r = u * 2 + rr;
                const int s = mb + i * 16 + quad * 4 + r;
                if (s < Ne) {
                    const int slot = toks[s];
                    const float v = ((red[0][i][r][lane] + red[1][i][r][lane]) +
                                     (red[2][i][r][lane] + red[3][i][r][lane])) * wsl[s];
                    atomicAdd(&out[(size_t)(slot >> 1) * DDIM + d0 + n], v);
                }
            }
        }
        __syncthreads();
    }
}

extern "C" void kernel_launch(void* const* d_in, const int* in_sizes, int n_in,
                              void* d_out, int out_size, void* d_ws, size_t ws_size,
                              hipStream_t stream)
{
    const float* x   = (const float*)d_in[0];
    const float* rs  = (const float*)d_in[1];
    const float* Wr  = (const float*)d_in[2];
    const float* G   = (const float*)d_in[3];
    const float* Wl  = (const float*)d_in[4];
    const float* pes = (const float*)d_in[5];
    float* out = (float*)d_out;

    char* ws = (char*)d_ws;
    int*   easgn = (int*)(ws);
    float* wts   = (float*)(ws + 4096);
    short* xb    = (short*)(ws + 8192);
    short* act   = (short*)(ws + 532480);

    router_kernel<<<dim3(LTOK), dim3(256), 0, stream>>>(x, rs, Wr, pes, easgn, wts, xb, out);
    gates_kernel<<<dim3(32, NEXP), dim3(256), 0, stream>>>(xb, G, easgn, act);
    linear_kernel<<<dim3(32, NEXP), dim3(256), 0, stream>>>(act, Wl, easgn, wts, out);
}

// Round 2
// 151.985 us; speedup vs baseline: 1.0474x; 1.0048x over previous
//
#include <hip/hip_runtime.h>
#include <hip/hip_bf16.h>
#include <math.h>

#define LTOK 512
#define DDIM 512
#define NEXP 32
#define HDIM 512

typedef __attribute__((ext_vector_type(8))) short short8;
typedef __attribute__((ext_vector_type(4))) float floatx4;

// round-to-nearest-even fp32->bf16, packed pair: low16 = rne(a), high16 = rne(b)
__device__ __forceinline__ unsigned bpack(float a, float b) {
    unsigned ua = __float_as_uint(a), ub = __float_as_uint(b);
    ua += 0x7FFFu + ((ua >> 16) & 1u);
    ub += 0x7FFFu + ((ub >> 16) & 1u);
    return (ua >> 16) | (ub & 0xFFFF0000u);
}

// Raw barrier WITHOUT the compiler's s_waitcnt vmcnt(0) drain (so in-flight
// weight loads stay in flight across it). Own-wave LDS ops drained for the
// scan's init/publish correctness; "memory" clobber pins LDS op order.
#define RAW_BARRIER() do { \
    asm volatile("s_waitcnt lgkmcnt(0)" ::: "memory"); \
    __builtin_amdgcn_s_barrier(); \
} while (0)

// ws layout (bytes):
//   [0, 4K)        easgn: int[1024]   easgn[2t+k] = expert of token t's k-th pick
//   [4K, 8K)       wts:   float[1024] = routing weight * per_expert_scale
//   [8K, +512K)    xb:    512x512 bf16 (x rounded to bf16)
//   [532480, +1M)  act:   1024x512 bf16 (slot-indexed activated gate output)

// 256 threads/token-block: 4 waves split the logits K-dim (64 Wr loads/lane).
__global__ __launch_bounds__(256) void router_kernel(
    const float* __restrict__ x, const float* __restrict__ rs,
    const float* __restrict__ Wr, const float* __restrict__ pes,
    int* __restrict__ easgn, float* __restrict__ wts,
    short* __restrict__ xb, float* __restrict__ out)
{
    const int t = blockIdx.x;
    const int tid = threadIdx.x;
    const int lane = tid & 63;
    const int wv = tid >> 6;

    float xv[2];
    float ss = 0.f;
#pragma unroll
    for (int j = 0; j < 2; ++j) {
        xv[j] = x[t * DDIM + j * 256 + tid];
        ss += xv[j] * xv[j];
    }
    // emit bf16 copy of x for the expert GEMMs; zero this token's out row
#pragma unroll
    for (int j = 0; j < 2; ++j) {
        xb[t * DDIM + j * 256 + tid] = (short)(bpack(xv[j], 0.f) & 0xFFFFu);
        out[t * DDIM + j * 256 + tid] = 0.f;
    }

#pragma unroll
    for (int o = 32; o > 0; o >>= 1) ss += __shfl_xor(ss, o);
    __shared__ float sred[4];
    if (lane == 0) sred[wv] = ss;
    __syncthreads();
    ss = (sred[0] + sred[1]) + (sred[2] + sred[3]);
    const float var = ss * (1.0f / 512.0f);
    const float coef = rsqrtf(var + 1e-6f) * rsqrtf(512.0f);

    __shared__ float ri[DDIM];
#pragma unroll
    for (int j = 0; j < 2; ++j) {
        const int d = j * 256 + tid;
        ri[d] = xv[j] * coef * rs[d];
    }
    __syncthreads();

    // logits: tid&31 -> expert, tid>>5 -> 1/8th of D (64 d each)
    const int e = tid & 31;
    const int seg = tid >> 5;
    const int dbeg = seg * 64;
    float l0 = 0.f, l1 = 0.f, l2 = 0.f, l3 = 0.f;
#pragma unroll 4
    for (int d = dbeg; d < dbeg + 64; d += 4) {
        l0 = fmaf(ri[d + 0], Wr[(d + 0) * NEXP + e], l0);
        l1 = fmaf(ri[d + 1], Wr[(d + 1) * NEXP + e], l1);
        l2 = fmaf(ri[d + 2], Wr[(d + 2) * NEXP + e], l2);
        l3 = fmaf(ri[d + 3], Wr[(d + 3) * NEXP + e], l3);
    }
    __shared__ float lpart[8][NEXP];
    lpart[seg][e] = (l0 + l1) + (l2 + l3);
    __syncthreads();

    __shared__ float lgs[NEXP];
    if (tid < NEXP) {
        float v = 0.f;
#pragma unroll
        for (int s = 0; s < 8; ++s) v += lpart[s][tid];
        lgs[tid] = v;
    }
    __syncthreads();

    if (tid == 0) {
        int i0 = 0; float m0 = lgs[0];
        for (int i = 1; i < NEXP; ++i) if (lgs[i] > m0) { m0 = lgs[i]; i0 = i; }
        int i1 = -1; float m1 = -1e30f;
        for (int i = 0; i < NEXP; ++i) if (i != i0 && lgs[i] > m1) { m1 = lgs[i]; i1 = i; }
        // softmax denom cancels against renorm: weights depend only on top-2 logits
        const float e1 = expf(m1 - m0);
        const float inv = 1.0f / (1.0f + e1);
        easgn[2 * t]     = i0;
        easgn[2 * t + 1] = i1;
        wts[2 * t]     = inv * pes[i0];
        wts[2 * t + 1] = e1 * inv * pes[i1];
    }
}

// grid (32, 32): blockIdx.x = 16-wide h tile, blockIdx.y = expert.
// 4 waves: wv = (khalf<<1)|gate. REGISTER staging this round: the wave's B
// chunk (16 h x 256 k fp32) is loaded straight to VGPRs (16 x dwordx4/lane,
// 64 B HBM granules fully used) and bpack'd from regs — no LDS stage, no
// DMA->LDS->ds_read hop. LDS drops 67.6 KB -> 10.3 KB; launch_bounds(256,4)
// -> 4 blocks/CU -> ALL 1024 blocks resident (one residency round).
// Scan overlap preserved: eg issued first, scan waits vmcnt(#weights) only
// (compiler per-use waits); weight loads stay in flight under it.
__global__ __launch_bounds__(256, 4) void gates_kernel(
    const short* __restrict__ xb, const float* __restrict__ G,
    const int* __restrict__ easgn, short* __restrict__ act)
{
    const int e  = blockIdx.y;
    const int h0 = blockIdx.x * 16;
    const int tid = threadIdx.x;
    const int wv   = tid >> 6;
    const int g    = wv & 1;    // gate index
    const int kh   = wv >> 1;   // K half
    const int lane = tid & 63;
    const int n    = lane & 15;
    const int quad = lane >> 4;

    __shared__ float red[4][2][4][64];   // 8 KB
    __shared__ int toks[LTOK];           // 2 KB
    __shared__ int lcnt;

    // easgn load issued FIRST (oldest vmem slot -> scan waits only on it)
    const int4 eg = ((const int4*)easgn)[tid];

    // ---- register stage: 16 x global_load_dwordx4 per lane ----
    const float* Gl = G + ((size_t)((e * 2 + g) * HDIM) + h0 + n) * DDIM + kh * 256 + quad * 8;
    floatx4 u0[8], u1[8];
#pragma unroll
    for (int ks = 0; ks < 8; ++ks) {
        u0[ks] = *(const floatx4*)(Gl + ks * 32);
        u1[ks] = *(const floatx4*)(Gl + ks * 32 + 4);
    }

    // ---- self-select scan, overlapped with the weight-load flight ----
    if (tid == 0) lcnt = 0;
    RAW_BARRIER();
    if (eg.x == e) { int p = atomicAdd(&lcnt, 1); toks[p] = 4 * tid; }
    if (eg.y == e) { int p = atomicAdd(&lcnt, 1); toks[p] = 4 * tid + 1; }
    if (eg.z == e) { int p = atomicAdd(&lcnt, 1); toks[p] = 4 * tid + 2; }
    if (eg.w == e) { int p = atomicAdd(&lcnt, 1); toks[p] = 4 * tid + 3; }
    RAW_BARRIER();
    const int Ne = lcnt;
    if (Ne == 0) return;   // reg loads drain automatically at wave end

    // ---- pack to MFMA B fragments (compiler inserts per-use vmcnt waits) ----
    short8 Bg[8];
#pragma unroll
    for (int ks = 0; ks < 8; ++ks) {
        union { short8 s; unsigned u[4]; } B;
        B.u[0] = bpack(u0[ks].x, u0[ks].y);
        B.u[1] = bpack(u0[ks].z, u0[ks].w);
        B.u[2] = bpack(u1[ks].x, u1[ks].y);
        B.u[3] = bpack(u1[ks].z, u1[ks].w);
        Bg[ks] = B.s;
    }

    const short* xbh = xb + kh * 256;

    for (int mb = 0; mb < Ne; mb += 32) {
        int arow[2];
#pragma unroll
        for (int i = 0; i < 2; ++i) {
            int s = mb + i * 16 + n;
            arow[i] = toks[s < Ne ? s : Ne - 1] >> 1;   // token index
        }
        floatx4 acc[2] = {};
#pragma unroll
        for (int ks = 0; ks < 8; ++ks) {
            const int ko = ks * 32 + quad * 8;
#pragma unroll
            for (int i = 0; i < 2; ++i) {
                const short8 A = *(const short8*)(xbh + (size_t)arow[i] * DDIM + ko);
                acc[i] = __builtin_amdgcn_mfma_f32_16x16x32_bf16(A, Bg[ks], acc[i], 0, 0, 0);
            }
        }
#pragma unroll
        for (int i = 0; i < 2; ++i)
#pragma unroll
            for (int r = 0; r < 4; ++r)
                red[wv][i][r][lane] = acc[i][r];
        __syncthreads();

        // epilogue: wave handles m-tile (wv&1), regs {2u,2u+1}, u=wv>>1.
        // C/D: col = lane&15, row = quad*4 + r.
        {
            const int i = wv & 1;
            const int u = wv >> 1;
#pragma unroll
            for (int rr = 0; rr < 2; ++rr) {
                const int r = u * 2 + rr;
                const int s = mb + i * 16 + quad * 4 + r;
                if (s < Ne) {
                    const int a = toks[s];   // slot id = act row
                    const float g0 = red[0][i][r][lane] + red[2][i][r][lane];
                    const float g1 = red[1][i][r][lane] + red[3][i][r][lane];
                    // gelu_tanh(g0) = g0 * sigmoid(2*u)
                    const float uu = 0.7978845608f * (g0 + 0.044715f * g0 * g0 * g0);
                    const float sg = 1.0f / (1.0f + __expf(-2.0f * uu));
                    const float v = g0 * sg * g1;
                    act[(size_t)a * HDIM + h0 + n] = (short)(bpack(v, 0.f) & 0xFFFFu);
                }
            }
        }
        __syncthreads();
    }
}

// grid (32, 32): blockIdx.x = 16-wide d tile, blockIdx.y = expert.
// 4 waves = K quarters (128 h). Register staging: 32 strided scalar loads/lane
// (same addresses the old stage4 DMA issued; 4x64B segments per instr, every
// byte consumed across the d-tile grid). LDS 44 -> 12.3 KB; 4 blocks/CU ->
// all 1024 blocks resident. Scan overlap preserved (eg/wt4 issued first).
__global__ __launch_bounds__(256, 4) void linear_kernel(
    const short* __restrict__ act, const float* __restrict__ Wl,
    const int* __restrict__ easgn, const float* __restrict__ wts,
    float* __restrict__ out)
{
    const int e  = blockIdx.y;
    const int d0 = blockIdx.x * 16;
    const int tid = threadIdx.x;
    const int wv   = tid >> 6;
    const int lane = tid & 63;
    const int n    = lane & 15;
    const int quad = lane >> 4;

    __shared__ float red[4][2][4][64];   // 8 KB
    __shared__ int   toks[LTOK];
    __shared__ float wsl[LTOK];
    __shared__ int   lcnt;

    // issued first: oldest vmem slots
    const int4 eg = ((const int4*)easgn)[tid];
    const float4 wt4 = ((const float4*)wts)[tid];

    // ---- register stage: 32 strided scalar loads per lane ----
    const float* Wbase = Wl + ((size_t)e * HDIM + wv * 128 + quad * 8) * DDIM + d0 + n;
    float w[32];
#pragma unroll
    for (int ks = 0; ks < 4; ++ks)
#pragma unroll
        for (int j = 0; j < 8; ++j)
            w[ks * 8 + j] = Wbase[(size_t)(ks * 32 + j) * DDIM];

    // ---- self-select scan, overlapped with the weight-load flight ----
    if (tid == 0) lcnt = 0;
    RAW_BARRIER();
    if (eg.x == e) { int p = atomicAdd(&lcnt, 1); toks[p] = 4 * tid;     wsl[p] = wt4.x; }
    if (eg.y == e) { int p = atomicAdd(&lcnt, 1); toks[p] = 4 * tid + 1; wsl[p] = wt4.y; }
    if (eg.z == e) { int p = atomicAdd(&lcnt, 1); toks[p] = 4 * tid + 2; wsl[p] = wt4.z; }
    if (eg.w == e) { int p = atomicAdd(&lcnt, 1); toks[p] = 4 * tid + 3; wsl[p] = wt4.w; }
    RAW_BARRIER();
    const int Ne = lcnt;
    if (Ne == 0) return;

    // ---- pack (compiler inserts per-use vmcnt waits) ----
    short8 Bl[4];
#pragma unroll
    for (int ks = 0; ks < 4; ++ks) {
        union { short8 s; unsigned u[4]; } B;
        B.u[0] = bpack(w[ks * 8 + 0], w[ks * 8 + 1]);
        B.u[1] = bpack(w[ks * 8 + 2], w[ks * 8 + 3]);
        B.u[2] = bpack(w[ks * 8 + 4], w[ks * 8 + 5]);
        B.u[3] = bpack(w[ks * 8 + 6], w[ks * 8 + 7]);
        Bl[ks] = B.s;
    }

    for (int mb = 0; mb < Ne; mb += 32) {
        int arow[2];
#pragma unroll
        for (int i = 0; i < 2; ++i) {
            int s = mb + i * 16 + n;
            arow[i] = toks[s < Ne ? s : Ne - 1];   // slot id = act row
        }
        floatx4 acc[2] = {};
#pragma unroll
        for (int ks = 0; ks < 4; ++ks) {
            const int ko = wv * 128 + ks * 32 + quad * 8;
#pragma unroll
            for (int i = 0; i < 2; ++i) {
                const short8 A = *(const short8*)(act + (size_t)arow[i] * HDIM + ko);
                acc[i] = __builtin_amdgcn_mfma_f32_16x16x32_bf16(A, Bl[ks], acc[i], 0, 0, 0);
            }
        }
#pragma unroll
        for (int i = 0; i < 2; ++i)
#pragma unroll
            for (int r = 0; r < 4; ++r)
                red[wv][i][r][lane] = acc[i][r];
        __syncthreads();

        {
            const int i = wv & 1;
            const int u = wv >> 1;
#pragma unroll
            for (int rr = 0; rr < 2; ++rr) {
                const int r = u * 2 + rr;
                const int s = mb + i * 16 + quad * 4 + r;
                if (s < Ne) {
                    const int slot = toks[s];
                    const float v = ((red[0][i][r][lane] + red[1][i][r][lane]) +
                                     (red[2][i][r][lane] + red[3][i][r][lane])) * wsl[s];
                    atomicAdd(&out[(size_t)(slot >> 1) * DDIM + d0 + n], v);
                }
            }
        }
        __syncthreads();
    }
}

extern "C" void kernel_launch(void* const* d_in, const int* in_sizes, int n_in,
                              void* d_out, int out_size, void* d_ws, size_t ws_size,
                              hipStream_t stream)
{
    const float* x   = (const float*)d_in[0];
    const float* rs  = (const float*)d_in[1];
    const float* Wr  = (const float*)d_in[2];
    const float* G   = (const float*)d_in[3];
    const float* Wl  = (const float*)d_in[4];
    const float* pes = (const float*)d_in[5];
    float* out = (float*)d_out;

    char* ws = (char*)d_ws;
    int*   easgn = (int*)(ws);
    float* wts   = (float*)(ws + 4096);
    short* xb    = (short*)(ws + 8192);
    short* act   = (short*)(ws + 532480);

    router_kernel<<<dim3(LTOK), dim3(256), 0, stream>>>(x, rs, Wr, pes, easgn, wts, xb, out);
    gates_kernel<<<dim3(32, NEXP), dim3(256), 0, stream>>>(xb, G, easgn, act);
    linear_kernel<<<dim3(32, NEXP), dim3(256), 0, stream>>>(act, Wl, easgn, wts, out);
}